// Round 6
// baseline (54.623 us; speedup 1.0000x reference)
//
#include <hip/hip_runtime.h>
#include <stdint.h>

#define GLOBAL_AS __attribute__((address_space(1)))
#define LDS_AS    __attribute__((address_space(3)))

typedef __attribute__((ext_vector_type(8))) __bf16 bf16x8;
typedef __attribute__((ext_vector_type(4))) float  f32x4;

static_assert(sizeof(bf16x8) == 16, "bf16x8 must be 16B");

constexpr int N  = 4096;     // B*P rows
constexpr int DK = 512;      // feature dim
constexpr int NTILE = 1056;  // sum_{rt=0..31} (2rt+2): 128x64 tiles covering lower triangle
constexpr int GRID_MAIN = 1024;
constexpr int PW = 96;       // partials width: 64 direct (gc) + 32 mirror (rt)

// ---------------------------------------------------------------------------
// ws layout:
//   Xb       : bf16 [4096][512]         @ 0            (4 MiB)  [dead after k_main]
//   cls      : int32[4096]              @ 4Mi           (16 KiB)
//   ctr      : int32[64]                @ 4Mi+16Ki      (256 B)   work-steal counter
//   partials : float4 [4096][96]        @ 4Mi+16Ki+256  (6 MiB)  {S,P,E,W}
//   blockSums: float[1024]              @ 0  (aliases dead Xb; same-stream safe)
// ---------------------------------------------------------------------------

// blocks 0..1023: fp32->bf16 convert. block 1024: build cls + init steal ctr.
__global__ void k_convert(const float* __restrict__ X, __bf16* __restrict__ Xb,
                          const int* __restrict__ tbuf, int* __restrict__ cls,
                          int* __restrict__ ctr) {
    if (blockIdx.x == 1024) {
        __shared__ int is64;
        const int t = threadIdx.x;          // 256 threads
        if (t == 0) { is64 = 1; ctr[0] = GRID_MAIN; }
        __syncthreads();
        // int64 targets => odd int32 words zero; inspect first 1024 words (OOB-safe)
        if (tbuf[4 * t + 1] != 0 || tbuf[4 * t + 3] != 0) is64 = 0;
        __syncthreads();
        const int f = is64;
#pragma unroll
        for (int q = 0; q < 4; ++q) {
            const int ti = 4 * t + q;
            const int v = tbuf[f ? 2 * ti : ti];
            cls[4 * ti + 0] = v; cls[4 * ti + 1] = v;
            cls[4 * ti + 2] = v; cls[4 * ti + 3] = v;
        }
        return;
    }
    int idx = blockIdx.x * blockDim.x + threadIdx.x;
    const float4* s = (const float4*)X;
    float4 a = s[2 * idx + 0];
    float4 b = s[2 * idx + 1];
    bf16x8 o;
    o[0] = (__bf16)a.x; o[1] = (__bf16)a.y; o[2] = (__bf16)a.z; o[3] = (__bf16)a.w;
    o[4] = (__bf16)b.x; o[5] = (__bf16)b.y; o[6] = (__bf16)b.z; o[7] = (__bf16)b.w;
    *(bf16x8*)(Xb + 8 * idx) = o;
}

// Triangular 128x64-tile fused GEMM+stats. 256 thr = 4 waves (2x2 grid), each
// wave 64x32 output. 3-deep LDS pipeline, BK=32, counted vmcnt (never full
// drain in-loop). Work-stealing persistent blocks (grid 1024, tiles 1056).
// Tile (rt,gc): rows [rt*128,+128), cols [gc*64,+64), gc < 2rt+2.
// fullyBelow (gc<2rt) additionally folds col-stats (mirror of symmetric prod).
// LDS ~38KB -> 4 blocks/CU; VGPR cap 128 (256thr,4 w/EU) -> 16 waves/CU.
__launch_bounds__(256, 4)
__global__ void k_main(const __bf16* __restrict__ Xb, const int* __restrict__ cls,
                       float* __restrict__ partials, int* __restrict__ ctr) {
    __shared__ __align__(16) char smem[3][12288];   // 3 bufs: 192 rows x 64B (A:128,B:64)
    __shared__ int rowcls[128], colcls[64];
    __shared__ int shsteal;
    float4* accR = (float4*)&smem[0][0];   // [2][128] row stats (epilogue alias)
    float4* accC = (float4*)&smem[1][0];   // [2][64]  col stats (epilogue alias)

    const int tid  = threadIdx.x;
    const int lane = tid & 63;
    const int wid  = tid >> 6;          // 0..3
    const int wr   = wid >> 1;          // 0..1 : rows wr*64..+63
    const int wc   = wid & 1;           // 0..1 : cols wc*32..+31
    const int rA   = lane & 15;
    const int kgrp = lane >> 4;
    const char* xb = (const char*)Xb;

    // XCD-aware bijective map over tile ids (1056 = 8*132)
    int tile = (blockIdx.x & 7) * 132 + (blockIdx.x >> 3);

    for (;;) {
        // decode tile -> (rt, gc): id = rt*(rt+1) + gc, gc in [0, 2rt+2)
        int rt = (int)((sqrtf(4.0f * (float)tile + 1.0f) - 1.0f) * 0.5f);
        while ((rt + 1) * (rt + 2) <= tile) ++rt;
        while (rt * (rt + 1) > tile) --rt;
        const int gc = tile - rt * (rt + 1);
        const int i0 = rt * 128;
        const int j0 = gc * 64;
        const bool fullyBelow = (gc < 2 * rt);

        if (tid < 128) rowcls[tid] = cls[i0 + tid];
        else if (tid < 192) colcls[tid - 128] = cls[j0 + (tid - 128)];
        __syncthreads();   // cls ready; prev tile fully done with aliased smem

        f32x4 acc[4][2] = {};

        // STAGE: 768 x 16B into buf: linear LDS dest (l*16), source pre-swizzled
        // (chunk ^ (row>>1)&3) so swizzled ds_read below matches (rule #21).
#define STAGE(bslot, kt)                                                                   \
        {                                                                                  \
            char* dst = &smem[(bslot)][0];                                                 \
            const size_t kb = (size_t)(kt) * 64;                                           \
            _Pragma("unroll")                                                              \
            for (int q = 0; q < 3; ++q) {                                                  \
                const int l    = q * 256 + tid;                                            \
                const int prow = l >> 2;                                                   \
                const int csrc = (l & 3) ^ ((prow >> 1) & 3);                              \
                const int grow = (prow < 128) ? (i0 + prow) : (j0 + prow - 128);           \
                __builtin_amdgcn_global_load_lds(                                          \
                    (const GLOBAL_AS void*)(xb + (size_t)grow * 1024 + kb + csrc * 16),    \
                    (LDS_AS void*)(dst + q * 4096 + wid * 1024), 16, 0, 0);                \
            }                                                                              \
        }

        STAGE(0, 0);
        STAGE(1, 1);

#pragma unroll
        for (int t = 0; t < 16; ++t) {
            // wait own stage-t loads (leave stage t+1 in flight), then sync:
            // every wave waited before arriving => all waves' stage-t landed.
            if (t < 15) { asm volatile("s_waitcnt vmcnt(3)" ::: "memory"); }
            else        { asm volatile("s_waitcnt vmcnt(0)" ::: "memory"); }
            __builtin_amdgcn_s_barrier();
            asm volatile("" ::: "memory");
            if (t + 2 < 16) STAGE((t + 2) % 3, t + 2);   // post-barrier: no overwrite race
            const char* bp = &smem[t % 3][0];
            bf16x8 af[4], bg[2];
#pragma unroll
            for (int m = 0; m < 4; ++m) {
                const int pr = wr * 64 + m * 16 + rA;
                af[m] = *(const bf16x8*)(bp + pr * 64 + ((kgrp ^ ((pr >> 1) & 3)) << 4));
            }
#pragma unroll
            for (int n = 0; n < 2; ++n) {
                const int pr = 128 + wc * 32 + n * 16 + rA;
                bg[n] = *(const bf16x8*)(bp + pr * 64 + ((kgrp ^ ((pr >> 1) & 3)) << 4));
            }
            // swapped operands: D[j][i] layout => i on rA axis, j on kgrp*4+reg
#pragma unroll
            for (int m = 0; m < 4; ++m)
#pragma unroll
                for (int n = 0; n < 2; ++n)
                    acc[m][n] = __builtin_amdgcn_mfma_f32_16x16x32_bf16(bg[n], af[m],
                                                                        acc[m][n], 0, 0, 0);
        }
#undef STAGE

        __syncthreads();   // all reads of smem bufs done -> stats aliases safe

        // epilogue: p(i,j), i = wr*64+m*16+rA, j = wc*32+n*16+kgrp*4+r
        // part(i) = rA&3, part(j) = r  (tile bases %4==0 / %4==0)
        const int pi = rA & 3;
        int ci[4];
#pragma unroll
        for (int m = 0; m < 4; ++m) ci[m] = rowcls[wr * 64 + m * 16 + rA];
        float rS[4] = {0.f, 0.f, 0.f, 0.f};
        float rP[4] = {0.f, 0.f, 0.f, 0.f};
        float rE[4] = {0.f, 0.f, 0.f, 0.f};
        float rW[4] = {0.f, 0.f, 0.f, 0.f};

#pragma unroll
        for (int n = 0; n < 2; ++n) {
#pragma unroll
            for (int r = 0; r < 4; ++r) {
                const int cj = colcls[wc * 32 + n * 16 + kgrp * 4 + r];
                float cS = 0.f, cP = 0.f, cE = 0.f, cW = 0.f;
#pragma unroll
                for (int m = 0; m < 4; ++m) {
                    const float p  = acc[m][n][r];
                    const float ep = __expf(p);
                    const bool sc = (ci[m] == cj);
                    const bool sp = (pi == r);
                    if (!sc && !sp) { rS[m] += ep; cS += ep; }   // dadc
                    const float w = (!sc && sp) ? 2.f : ((sc && !sp) ? 1.f : 0.f);
                    rP[m] += w * p;  rE[m] += w * ep;  rW[m] += w;
                    cP += w * p;     cE += w * ep;     cW += w;
                }
                if (fullyBelow) {   // reduce over i (rA axis)
#pragma unroll
                    for (int off = 1; off < 16; off <<= 1) {
                        cS += __shfl_xor(cS, off);
                        cP += __shfl_xor(cP, off);
                        cE += __shfl_xor(cE, off);
                        cW += __shfl_xor(cW, off);
                    }
                    if (rA == 0)
                        accC[wr * 64 + wc * 32 + n * 16 + kgrp * 4 + r] =
                            make_float4(cS, cP, cE, cW);
                }
            }
        }
        // row stats: reduce over j (kgrp axis): 2 shfl steps
#pragma unroll
        for (int m = 0; m < 4; ++m) {
            float vS = rS[m], vP = rP[m], vE = rE[m], vW = rW[m];
            vS += __shfl_xor(vS, 16); vS += __shfl_xor(vS, 32);
            vP += __shfl_xor(vP, 16); vP += __shfl_xor(vP, 32);
            vE += __shfl_xor(vE, 16); vE += __shfl_xor(vE, 32);
            vW += __shfl_xor(vW, 16); vW += __shfl_xor(vW, 32);
            if (kgrp == 0) accR[wc * 128 + wr * 64 + m * 16 + rA] = make_float4(vS, vP, vE, vW);
        }

        __syncthreads();
        if (tid < 128) {   // fixed-order sums => deterministic
            float4 a0 = accR[tid], a1 = accR[128 + tid];
            ((float4*)partials)[(size_t)(i0 + tid) * PW + gc] =
                make_float4(a0.x + a1.x, a0.y + a1.y, a0.z + a1.z, a0.w + a1.w);
        } else if (tid < 192 && fullyBelow) {
            const int c = tid - 128;
            float4 c0 = accC[c], c1 = accC[64 + c];
            ((float4*)partials)[(size_t)(j0 + c) * PW + 64 + rt] =
                make_float4(c0.x + c1.x, c0.y + c1.y, c0.z + c1.z, c0.w + c1.w);
        }

        // steal next tile (deterministic output: tiles write disjoint fixed slots)
        if (tid == 0) shsteal = atomicAdd(ctr, 1);
        __syncthreads();
        const int t2 = shsteal;
        if (t2 >= NTILE) break;
        tile = (t2 & 7) * 132 + (t2 >> 3);
    }
}

// 1 row per wave; sum only the slots k_main actually wrote for this row:
// direct gc in [0, 2*(row>>7)+2), mirror rt in [((row>>6)+2)>>1, 32).
__global__ void k_rowloss(const float* __restrict__ partials, float* __restrict__ blockSums) {
    __shared__ float red[4];
    const int tid = threadIdx.x;
    const int lane = tid & 63;
    const int w = tid >> 6;
    const int row = blockIdx.x * 4 + w;
    const int dEnd   = 2 * (row >> 7) + 2;
    const int mStart = ((row >> 6) + 2) >> 1;

    const float4* p = (const float4*)partials + (size_t)row * PW;
    float S = 0.f, P = 0.f, E = 0.f, W_ = 0.f;
#pragma unroll
    for (int s = lane; s < PW; s += 64) {
        const bool valid = (s < 64) ? (s < dEnd) : ((s - 64) >= mStart);
        if (valid) {
            float4 v = p[s];
            S += v.x; P += v.y; E += v.z; W_ += v.w;
        }
    }
#pragma unroll
    for (int off = 1; off < 64; off <<= 1) {
        S += __shfl_xor(S, off);
        P += __shfl_xor(P, off);
        E += __shfl_xor(E, off);
        W_ += __shfl_xor(W_, off);
    }
    if (lane == 0) red[w] = W_ * logf(S) - P + E / S;
    __syncthreads();
    if (tid == 0) blockSums[blockIdx.x] = red[0] + red[1] + red[2] + red[3];
}

__global__ void k_final2(const float* __restrict__ blockSums, float* __restrict__ out) {
    __shared__ float red[4];
    const int t = threadIdx.x;   // 256
    float v = blockSums[t] + blockSums[t + 256] + blockSums[t + 512] + blockSums[t + 768];
#pragma unroll
    for (int off = 1; off < 64; off <<= 1) v += __shfl_xor(v, off);
    if ((t & 63) == 0) red[t >> 6] = v;
    __syncthreads();
    if (t == 0) out[0] = (red[0] + red[1] + red[2] + red[3]) / (float)N;
}

extern "C" void kernel_launch(void* const* d_in, const int* in_sizes, int n_in,
                              void* d_out, int out_size, void* d_ws, size_t ws_size,
                              hipStream_t stream) {
    const float* X = (const float*)d_in[0];
    const int*   T = (const int*)d_in[1];
    float* out = (float*)d_out;

    char* ws = (char*)d_ws;
    __bf16* Xb    = (__bf16*)ws;
    int*    cls   = (int*)(ws + (size_t)4 * 1024 * 1024);
    int*    ctr   = (int*)(ws + (size_t)4 * 1024 * 1024 + 16 * 1024);
    float*  parts = (float*)(ws + (size_t)4 * 1024 * 1024 + 16 * 1024 + 256);
    float*  bsums = (float*)ws;   // aliases Xb (dead after k_main; same-stream ordering)

    hipLaunchKernelGGL(k_convert, dim3(1025), dim3(256), 0, stream, X, Xb, T, cls, ctr);
    hipLaunchKernelGGL(k_main,    dim3(GRID_MAIN), dim3(256), 0, stream, Xb, cls, parts, ctr);
    hipLaunchKernelGGL(k_rowloss, dim3(1024), dim3(256), 0, stream, parts, bsums);
    hipLaunchKernelGGL(k_final2,  dim3(1),    dim3(256), 0, stream, bsums, out);
}